// Round 7
// baseline (502.303 us; speedup 1.0000x reference)
//
#include <hip/hip_runtime.h>
#include <hip/hip_fp16.h>
#include <hip/hip_bf16.h>

// SlotAttention restructured:
//  dots = qs . x   with qs = LN(slots) @ (scale * Wq^T Wk)   (K never materialized)
//  updates = (N/wsum) * (sum_j w_j x_j) @ Wv^T               (V never materialized)
// x = LN(inputs) stored once as fp16. Output fp32.
// R6: k_tail still ~105us/call (serialized load->cvt->fma, 24 VALU/16B).
// R7: k_tail v3 -- packed fp16 math (__hfma2, 8 VALU/16B), fully-unrolled
// 8-uint4 dot groups (loads hoistable), 1024 thr/block (4 waves/SIMD),
// K-split-4 for 256-col phases, all GEMM operands as LDS half (broadcast reads).

#define BB 64
#define NN 4096
#define DD 256
#define NSL 8
#define NITER 3

__device__ __forceinline__ float wredsum(float v){
#pragma unroll
  for(int m=32;m;m>>=1) v += __shfl_xor(v, m, 64);
  return v;
}
__device__ __forceinline__ float2 u2f2(unsigned u){ __half2 h; __builtin_memcpy(&h,&u,4); return __half22float2(h); }
__device__ __forceinline__ float sigm(float v){ return 1.0f/(1.0f+__expf(-v)); }

union U4 { uint4 u; __half2 h[4]; };

// dot over K=64 halves for 2 rows. W: global fp16 (16B aligned). X0/X1: LDS half rows
// (pre-offset to k0, 16B aligned). fp16 accum chains of 16 half2, fp32 result.
__device__ __forceinline__ void dot2(const __half* __restrict__ W,
                                     const __half* X0, const __half* X1,
                                     float& r0, float& r1){
  const uint4* w4 = (const uint4*)W;
  const uint4* xa4 = (const uint4*)X0;
  const uint4* xb4 = (const uint4*)X1;
  __half2 z = __float2half2_rn(0.f);
  __half2 a0=z,a1=z,b0=z,b1=z;
#pragma unroll
  for(int kk=0;kk<8;kk++){
    U4 w; w.u = w4[kk];
    U4 xa; xa.u = xa4[kk];
    U4 xb; xb.u = xb4[kk];
    a0=__hfma2(w.h[0],xa.h[0],a0); a1=__hfma2(w.h[1],xa.h[1],a1);
    a0=__hfma2(w.h[2],xa.h[2],a0); a1=__hfma2(w.h[3],xa.h[3],a1);
    b0=__hfma2(w.h[0],xb.h[0],b0); b1=__hfma2(w.h[1],xb.h[1],b1);
    b0=__hfma2(w.h[2],xb.h[2],b0); b1=__hfma2(w.h[3],xb.h[3],b1);
  }
  float2 fa0=__half22float2(a0), fa1=__half22float2(a1);
  float2 fb0=__half22float2(b0), fb1=__half22float2(b1);
  r0 += (fa0.x+fa0.y)+(fa1.x+fa1.y);
  r1 += (fb0.x+fb0.y)+(fb1.x+fb1.y);
}

// ---------------- prep: fp16 weight casts (original layout) + slots broadcast ----------------
__global__ __launch_bounds__(256) void k_prep(
    const float* __restrict__ Wih, const float* __restrict__ Whh,
    const float* __restrict__ W1,  const float* __restrict__ W2,
    const float* __restrict__ Wv,  const float* __restrict__ sinit,
    __half* __restrict__ Wihh, __half* __restrict__ Whhh,
    __half* __restrict__ W1h,  __half* __restrict__ W2h,
    __half* __restrict__ Wvh,  float* __restrict__ slots){
  for(int idx = blockIdx.x*256 + threadIdx.x; idx < 1114112; idx += gridDim.x*256){
    if(idx < 196608) Wihh[idx] = __float2half(Wih[idx]);
    else if(idx < 393216){ int k=idx-196608; Whhh[k]=__float2half(Whh[k]); }
    else if(idx < 655360){ int k=idx-393216; W1h[k]=__float2half(W1[k]); }
    else if(idx < 917504){ int k=idx-655360; W2h[k]=__float2half(W2[k]); }
    else if(idx < 983040){ int k=idx-917504; Wvh[k]=__float2half(Wv[k]); }
    else { int k=idx-983040; slots[k] = sinit[k&2047]; }
  }
}

// ---------------- M2[c][e] = scale * (Wq^T Wk)[e][c]  (fp16, per-out-col rows) ----------------
__global__ __launch_bounds__(256) void k_M(const float* __restrict__ Wq, const float* __restrict__ Wk,
                                           __half* __restrict__ M2h){
  int c = blockIdx.x, e = threadIdx.x;
  float acc = 0.f;
#pragma unroll 8
  for(int d=0; d<256; d++) acc += Wq[d*256+e]*Wk[d*256+c];
  M2h[c*256+e] = __float2half(acc * 0.0625f);  // 256^-0.5
}

// ---------------- x = LN(inputs) -> fp16 ----------------
__global__ __launch_bounds__(256) void k_ln_x(const float* __restrict__ in, const float* __restrict__ g,
                                              const float* __restrict__ bbv, __half* __restrict__ x){
  int row  = blockIdx.x*4 + (threadIdx.x>>6);
  int lane = threadIdx.x&63;
  const float4 v = ((const float4*)(in + (size_t)row*DD))[lane];
  float s  = v.x+v.y+v.z+v.w;
  float ss = v.x*v.x+v.y*v.y+v.z*v.z+v.w*v.w;
  s = wredsum(s); ss = wredsum(ss);
  float m = s*(1.0f/256.0f);
  float r = rsqrtf(ss*(1.0f/256.0f) - m*m + 1e-5f);
  float4 gv = ((const float4*)g)[lane];
  float4 bv = ((const float4*)bbv)[lane];
  float y0=(v.x-m)*r*gv.x+bv.x, y1=(v.y-m)*r*gv.y+bv.y;
  float y2=(v.z-m)*r*gv.z+bv.z, y3=(v.w-m)*r*gv.w+bv.w;
  __half2 h0=__floats2half2_rn(y0,y1), h1=__floats2half2_rn(y2,y3);
  uint2 u; __builtin_memcpy(&u.x,&h0,4); __builtin_memcpy(&u.y,&h1,4);
  ((uint2*)(x + (size_t)row*DD))[lane] = u;
}

// ---------------- initial qs = LN(slots) @ M (once, before iter 0) ----------------
__global__ __launch_bounds__(256) void k_pre(const float* __restrict__ slots, const float* __restrict__ g,
                                             const float* __restrict__ bbv, const __half* __restrict__ M2h,
                                             float* __restrict__ qs){
  int row = blockIdx.x;      // 0..511 = b*8+i
  int t = threadIdx.x;
  __shared__ __align__(16) float sn[256];
  __shared__ float red[8];
  float v = slots[row*256 + t];
  float s = wredsum(v), ss = wredsum(v*v);
  int wid=t>>6, lane=t&63;
  if(lane==0){ red[wid]=s; red[4+wid]=ss; }
  __syncthreads();
  float S  = red[0]+red[1]+red[2]+red[3];
  float SS = red[4]+red[5]+red[6]+red[7];
  float m = S*(1.0f/256.0f);
  float r = rsqrtf(SS*(1.0f/256.0f) - m*m + 1e-5f);
  sn[t] = (v-m)*r*g[t]+bbv[t];
  __syncthreads();
  const uint4* w4 = (const uint4*)(M2h + (size_t)t*256);
  float acc=0.f;
#pragma unroll 4
  for(int kk=0;kk<32;kk++){
    U4 w; w.u=w4[kk];
#pragma unroll
    for(int q=0;q<4;q++){
      float2 f=__half22float2(w.h[q]);
      acc += sn[kk*8+2*q]*f.x + sn[kk*8+2*q+1]*f.y;
    }
  }
  qs[row*256+t]=acc;
}

// ---------------- fused attention pass: dots+softmax+eps -> w (LDS) -> partial agg ----------------
// grid 1024 (16 blocks/batch, 256 j-rows each), 256 threads
__global__ __launch_bounds__(256) void k_att(const __half* __restrict__ x, const float* __restrict__ qs,
                                             float* __restrict__ pagg){
  int b = blockIdx.x>>4;
  int t = threadIdx.x;
  size_t j = (size_t)blockIdx.x*256 + t;
  __shared__ __align__(16) float qt[256][8];     // qs transposed [c][i]
  __shared__ __align__(16) float wl[256][8];     // softmax weights per row
  __shared__ __align__(16) float aggl[4][2048];
  __shared__ float wsl[4][8];
  const float* qb = qs + b*2048;
  for(int e=t;e<2048;e+=256) qt[e&255][e>>8]=qb[e];
  __syncthreads();
  const uint4* xr = (const uint4*)(x + j*DD);
  float pd[8]={0,0,0,0,0,0,0,0};
#pragma unroll 2
  for(int ch=0; ch<32; ch++){
    uint4 u = xr[ch];
    float2 f0=u2f2(u.x), f1=u2f2(u.y), f2=u2f2(u.z), f3=u2f2(u.w);
    float xv[8]={f0.x,f0.y,f1.x,f1.y,f2.x,f2.y,f3.x,f3.y};
    int c0=ch*8;
#pragma unroll
    for(int cc=0;cc<8;cc++){
      const float4* qp=(const float4*)&qt[c0+cc][0];
      float4 qa=qp[0], qc=qp[1];
      float xvv=xv[cc];
      pd[0]+=qa.x*xvv; pd[1]+=qa.y*xvv; pd[2]+=qa.z*xvv; pd[3]+=qa.w*xvv;
      pd[4]+=qc.x*xvv; pd[5]+=qc.y*xvv; pd[6]+=qc.z*xvv; pd[7]+=qc.w*xvv;
    }
  }
  float mx=pd[0];
#pragma unroll
  for(int i=1;i<8;i++) mx=fmaxf(mx,pd[i]);
  float ev[8]; float ssum=0.f;
#pragma unroll
  for(int i=0;i<8;i++){ ev[i]=__expf(pd[i]-mx); ssum+=ev[i]; }
  float inv=1.0f/ssum;
#pragma unroll
  for(int i=0;i<8;i++) wl[t][i]=ev[i]*inv+1e-5f;
  __syncthreads();
  int wid=t>>6, lane=t&63;
  float acc[8][4];
#pragma unroll
  for(int i=0;i<8;i++){ acc[i][0]=0;acc[i][1]=0;acc[i][2]=0;acc[i][3]=0; }
  float ws[8]={0,0,0,0,0,0,0,0};
  for(int r=0;r<64;r++){
    int jl = wid*64 + r;
    uint2 u = ((const uint2*)(x + ((size_t)blockIdx.x*256 + jl)*DD))[lane];
    float2 f01=u2f2(u.x), f23=u2f2(u.y);
    const float4* wp=(const float4*)&wl[jl][0];
    float4 wa=wp[0], wb_=wp[1];
    float wv[8]={wa.x,wa.y,wa.z,wa.w,wb_.x,wb_.y,wb_.z,wb_.w};
    float xv[4]={f01.x,f01.y,f23.x,f23.y};
#pragma unroll
    for(int i=0;i<8;i++){
      acc[i][0]+=wv[i]*xv[0]; acc[i][1]+=wv[i]*xv[1];
      acc[i][2]+=wv[i]*xv[2]; acc[i][3]+=wv[i]*xv[3];
      ws[i]+=wv[i];
    }
  }
#pragma unroll
  for(int i=0;i<8;i++){
    float4 st={acc[i][0],acc[i][1],acc[i][2],acc[i][3]};
    *((float4*)&aggl[wid][i*256 + lane*4])=st;
  }
  if(lane==0){
#pragma unroll
    for(int i=0;i<8;i++) wsl[wid][i]=ws[i];
  }
  __syncthreads();
  float* pb = pagg + (size_t)blockIdx.x*2064;
  for(int e=t;e<2048;e+=256) pb[e]=aggl[0][e]+aggl[1][e]+aggl[2][e]+aggl[3][e];
  if(t<8) pb[2048+t]=wsl[0][t]+wsl[1][t]+wsl[2][t]+wsl[3][t];
}

// ---------------- fused tail v3: upd -> gates -> GRU -> LN -> MLP -> (slot-LN + qs) ----------------
// grid 256 (4 blocks/batch, 2 slot-rows each), 1024 threads. Packed-fp16 MACs.
__global__ __launch_bounds__(1024) void k_tail(
    const float* __restrict__ pagg, const __half* __restrict__ Wvh,
    const float* __restrict__ slots_in,
    const __half* __restrict__ Wihh, const __half* __restrict__ Whhh,
    const float* __restrict__ bih, const float* __restrict__ bhh,
    const float* __restrict__ lm_g, const float* __restrict__ lm_b,
    const __half* __restrict__ W1h, const float* __restrict__ b1,
    const __half* __restrict__ W2h, const float* __restrict__ b2,
    const float* __restrict__ ls_g, const float* __restrict__ ls_b,
    const __half* __restrict__ M2h,
    float* __restrict__ slots_out, float* __restrict__ qs_out, int last){
  int blk=blockIdx.x;            // 0..255
  int b=blk>>2, rq=blk&3;        // slot rows b*8 + rq*2 + {0,1}
  int t=threadIdx.x;
  int roff=rq*2;
  __shared__ float sb[512], hl[512];
  __shared__ float gl[3072];
  __shared__ float pp[4][2][256];
  __shared__ __align__(16) __half aggh[512], sbh[512], updh[512], ysh[512], z1h[2048];
  __shared__ float fac[2];
  __shared__ float redS[2][4], redQ[2][4];

  const float* pb = pagg + (size_t)b*16*2064;
  // ---- A0: reduce pagg partials + load slots (fp32 + half mirrors)
  if(t<512){
    float s=0.f;
#pragma unroll
    for(int k2=0;k2<16;k2++) s += pb[k2*2064 + roff*256 + t];
    aggh[t]=__float2half(s);
    float sv = slots_in[(size_t)b*2048 + roff*256 + t];
    sb[t]=sv; sbh[t]=__float2half(sv);
  }
  if(t<2){
    float s=0.f;
#pragma unroll
    for(int k2=0;k2<16;k2++) s += pb[k2*2064 + 2048 + roff + t];
    fac[t]=4096.0f/s;
  }
  __syncthreads();
  // ---- A1: upd = (agg @ Wv^T)*fac ; 256 cols x 4 K-quarters
  {
    int col=t&255, kq=t>>8;
    float r0=0.f,r1=0.f;
    dot2(Wvh + (size_t)col*256 + kq*64, aggh + kq*64, aggh + 256 + kq*64, r0, r1);
    pp[kq][0][col]=r0; pp[kq][1][col]=r1;
  }
  __syncthreads();
  if(t<512){
    int r=t>>8, col=t&255;
    float u=(pp[0][r][col]+pp[1][r][col]+pp[2][r][col]+pp[3][r][col])*fac[r];
    updh[r*256+col]=__float2half(u);
  }
  __syncthreads();
  // ---- B: gate GEMMs -> gl[r*1536 + col], col 0..767 = ih(upd), 768..1535 = hh(slots)
  {
    int col=t;   // 0..1023
    const __half* W; const __half* X; float bv;
    if(col<768){ W=Wihh+(size_t)col*256; X=updh; bv=bih[col]; }
    else       { W=Whhh+(size_t)(col-768)*256; X=sbh; bv=bhh[col-768]; }
    float r0=0.f,r1=0.f;
#pragma unroll
    for(int g2=0;g2<4;g2++) dot2(W+g2*64, X+g2*64, X+256+g2*64, r0, r1);
    gl[col]=r0+bv; gl[1536+col]=r1+bv;
  }
  if(t<512){
    int col=1024+t;  // hh cols 256..767
    const __half* W=Whhh+(size_t)(col-768)*256;
    float r0=0.f,r1=0.f;
#pragma unroll
    for(int g2=0;g2<4;g2++) dot2(W+g2*64, sbh+g2*64, sbh+256+g2*64, r0, r1);
    float bv=bhh[col-768];
    gl[col]=r0+bv; gl[1536+col]=r1+bv;
  }
  __syncthreads();
  // ---- C: GRU nonlinearity + LN stats
  if(t<512){
    int r=t>>8, cl=t&255;
    const float* gr=&gl[r*1536];
    float gir=gr[cl], giz=gr[256+cl], gin=gr[512+cl];
    float ghr=gr[768+cl], ghz=gr[1024+cl], ghn=gr[1280+cl];
    float hp = sb[r*256+cl];
    float rr=sigm(gir+ghr), z=sigm(giz+ghz);
    float n=tanhf(gin + rr*ghn);
    float hv=(1.0f-z)*n + z*hp;
    hl[r*256+cl]=hv;
    float s=wredsum(hv), ss=wredsum(hv*hv);
    if((t&63)==0){ redS[r][(t>>6)&3]=s; redQ[r][(t>>6)&3]=ss; }
  }
  __syncthreads();
  if(t<512){
    int r=t>>8, cl=t&255;
    float S =redS[r][0]+redS[r][1]+redS[r][2]+redS[r][3];
    float SS=redQ[r][0]+redQ[r][1]+redQ[r][2]+redQ[r][3];
    float m=S*(1.0f/256.0f);
    float rs=rsqrtf(SS*(1.0f/256.0f)-m*m+1e-5f);
    ysh[r*256+cl]=__float2half((hl[r*256+cl]-m)*rs*lm_g[cl]+lm_b[cl]);
  }
  __syncthreads();
  // ---- D: mlp up-proj + leaky relu -> z1h (half)
  {
    int col=t;
    const __half* W=W1h+(size_t)col*256;
    float r0=0.f,r1=0.f;
#pragma unroll
    for(int g2=0;g2<4;g2++) dot2(W+g2*64, ysh+g2*64, ysh+256+g2*64, r0, r1);
    float bv=b1[col];
    r0+=bv; r1+=bv;
    z1h[col]     =__float2half(r0>0.f?r0:0.01f*r0);
    z1h[1024+col]=__float2half(r1>0.f?r1:0.01f*r1);
  }
  __syncthreads();
  // ---- E: mlp down-proj (K=1024, 4 K-quarters)
  {
    int col=t&255, kq=t>>8;
    const __half* W=W2h+(size_t)col*1024+kq*256;
    float r0=0.f,r1=0.f;
#pragma unroll
    for(int g2=0;g2<4;g2++) dot2(W+g2*64, z1h+kq*256+g2*64, z1h+1024+kq*256+g2*64, r0, r1);
    pp[kq][0][col]=r0; pp[kq][1][col]=r1;
  }
  __syncthreads();
  // ---- E2: residual + slots write (+ LN stats for next iter)
  float v=0.f; int r_=0, cl_=0;
  if(t<512){
    r_=t>>8; cl_=t&255;
    v = hl[r_*256+cl_] + pp[0][r_][cl_]+pp[1][r_][cl_]+pp[2][r_][cl_]+pp[3][r_][cl_] + b2[cl_];
    slots_out[(size_t)b*2048 + (roff+r_)*256 + cl_]=v;
    if(!last){
      float s=wredsum(v), ss=wredsum(v*v);
      if((t&63)==0){ redS[r_][(t>>6)&3]=s; redQ[r_][(t>>6)&3]=ss; }
    }
  }
  if(last) return;
  __syncthreads();
  // ---- F: slot-LN + qs for next iteration
  if(t<512){
    float S =redS[r_][0]+redS[r_][1]+redS[r_][2]+redS[r_][3];
    float SS=redQ[r_][0]+redQ[r_][1]+redQ[r_][2]+redQ[r_][3];
    float m=S*(1.0f/256.0f);
    float rs=rsqrtf(SS*(1.0f/256.0f)-m*m+1e-5f);
    ysh[r_*256+cl_]=__float2half((v-m)*rs*ls_g[cl_]+ls_b[cl_]);
  }
  __syncthreads();
  {
    int col=t&255, kq=t>>8;
    float r0=0.f,r1=0.f;
    dot2(M2h + (size_t)col*256 + kq*64, ysh + kq*64, ysh + 256 + kq*64, r0, r1);
    pp[kq][0][col]=r0; pp[kq][1][col]=r1;
  }
  __syncthreads();
  if(t<512){
    int r=t>>8, col=t&255;
    qs_out[(size_t)b*2048 + (roff+r)*256 + col] = pp[0][r][col]+pp[1][r][col]+pp[2][r][col]+pp[3][r][col];
  }
}

extern "C" void kernel_launch(void* const* d_in, const int* in_sizes, int n_in,
                              void* d_out, int out_size, void* d_ws, size_t ws_size,
                              hipStream_t stream){
  const float* inputs=(const float*)d_in[0];
  const float* sinit =(const float*)d_in[1];
  const float* Wq =(const float*)d_in[2];
  const float* Wk =(const float*)d_in[3];
  const float* Wv =(const float*)d_in[4];
  const float* Wih=(const float*)d_in[5];
  const float* Whh=(const float*)d_in[6];
  const float* bih=(const float*)d_in[7];
  const float* bhh=(const float*)d_in[8];
  const float* lin_g=(const float*)d_in[9];
  const float* lin_b=(const float*)d_in[10];
  const float* ls_g=(const float*)d_in[11];
  const float* ls_b=(const float*)d_in[12];
  const float* lm_g=(const float*)d_in[13];
  const float* lm_b=(const float*)d_in[14];
  const float* W1=(const float*)d_in[15];
  const float* b1=(const float*)d_in[16];
  const float* W2=(const float*)d_in[17];
  const float* b2=(const float*)d_in[18];

  char* w=(char*)d_ws;
  __half* x   =(__half*)w; w += (size_t)BB*NN*DD*2;         // 134.2 MB
  float* qs   =(float*)w;  w += 512*256*4;
  float* slots=(float*)w;  w += 512*256*4;
  float* pagg =(float*)w;  w += (size_t)1024*2064*4;        // 8.45 MB
  __half* M2h =(__half*)w; w += 256*256*2;
  __half* Wihh=(__half*)w; w += 768*256*2;
  __half* Whhh=(__half*)w; w += 768*256*2;
  __half* W1h =(__half*)w; w += 1024*256*2;
  __half* W2h =(__half*)w; w += 256*1024*2;
  __half* Wvh =(__half*)w; w += 256*256*2;

  hipLaunchKernelGGL(k_prep, dim3(1088), dim3(256), 0, stream,
                     Wih,Whh,W1,W2,Wv,sinit, Wihh,Whhh,W1h,W2h,Wvh,slots);
  hipLaunchKernelGGL(k_M,    dim3(256),  dim3(256), 0, stream, Wq, Wk, M2h);
  hipLaunchKernelGGL(k_ln_x, dim3(65536),dim3(256), 0, stream, inputs, lin_g, lin_b, x);
  hipLaunchKernelGGL(k_pre,  dim3(512),  dim3(256), 0, stream, slots, ls_g, ls_b, M2h, qs);
  for(int it=0; it<NITER; ++it){
    int last = (it==NITER-1);
    float* dst = last ? (float*)d_out : slots;
    hipLaunchKernelGGL(k_att,  dim3(1024), dim3(256), 0, stream, x, qs, pagg);
    hipLaunchKernelGGL(k_tail, dim3(256),  dim3(1024), 0, stream,
                       pagg, Wvh, slots, Wihh, Whhh, bih, bhh,
                       lm_g, lm_b, W1h, b1, W2h, b2, ls_g, ls_b, M2h,
                       dst, qs, last);
  }
}

// Round 8
// 430.270 us; speedup vs baseline: 1.1674x; 1.1674x over previous
//
#include <hip/hip_runtime.h>
#include <hip/hip_fp16.h>
#include <hip/hip_bf16.h>

// SlotAttention restructured:
//  dots = qs . x   with qs = LN(slots) @ (scale * Wq^T Wk)   (K never materialized)
//  updates folded:  gates_ih = (agg*fac) @ (Wih@Wv)^T        (V and upd never materialized)
// x = LN(inputs) stored once as fp16. fp32 accumulation. Output fp32.
// R7 (regressed): fused tail = per-col GEMV, no weight reuse, ~110us/call.
// R8: tail as 6 small LDS-staged GEMM kernels (32x64 tiles, 8 out/thread,
// fp32 accum, K-major fp16 weights), Wv folded into WC=Wih@Wv, mlp2 K-split 8.

#define BB 64
#define NN 4096
#define DD 256
#define NSL 8
#define NITER 3

__device__ __forceinline__ float wredsum(float v){
#pragma unroll
  for(int m=32;m;m>>=1) v += __shfl_xor(v, m, 64);
  return v;
}
__device__ __forceinline__ float2 u2f2(unsigned u){ __half2 h; __builtin_memcpy(&h,&u,4); return __half22float2(h); }
__device__ __forceinline__ float sigm(float v){ return 1.0f/(1.0f+__expf(-v)); }

union U4 { uint4 u; __half2 h[4]; };

__device__ __forceinline__ void st8(float* dst, uint4 uu){
  U4 v; v.u=uu;
  float2 f0=__half22float2(v.h[0]), f1=__half22float2(v.h[1]),
         f2=__half22float2(v.h[2]), f3=__half22float2(v.h[3]);
  dst[0]=f0.x; dst[1]=f0.y; dst[2]=f1.x; dst[3]=f1.y;
  dst[4]=f2.x; dst[5]=f2.y; dst[6]=f3.x; dst[7]=f3.y;
}

// ---------------- prep: K-major fp16 weights + slots broadcast ----------------
__global__ __launch_bounds__(256) void k_prep(
    const float* __restrict__ Whh, const float* __restrict__ W1,
    const float* __restrict__ W2,  const float* __restrict__ sinit,
    __half* __restrict__ Wg, __half* __restrict__ W1t, __half* __restrict__ W2t,
    float* __restrict__ slots, __half* __restrict__ slotsh){
  for(int idx=blockIdx.x*256+threadIdx.x; idx<851968; idx+=gridDim.x*256){
    if(idx<196608){ int col=idx>>8, c=idx&255; Wg[(size_t)c*1536+768+col]=__float2half(Whh[idx]); }
    else if(idx<458752){ int k=idx-196608; int col=k>>8, c=k&255; W1t[(size_t)c*1024+col]=__float2half(W1[k]); }
    else if(idx<720896){ int k=idx-458752; int col=k>>10, c=k&1023; W2t[(size_t)c*256+col]=__float2half(W2[k]); }
    else { int k=idx-720896; float v=sinit[k&2047]; slots[k]=v; slotsh[k]=__float2half(v); }
  }
}

// ---------------- WC = Wih @ Wv  -> Wg cols 0..767 (K-major) ----------------
__global__ __launch_bounds__(256) void k_WC(const float* __restrict__ Wih, const float* __restrict__ Wv,
                                            __half* __restrict__ Wg){
  int col=blockIdx.x;  // 0..767
  int t=threadIdx.x;   // k 0..255
  __shared__ float wr[256];
  wr[t]=Wih[col*256+t];
  __syncthreads();
  float acc=0.f;
#pragma unroll 8
  for(int d=0;d<256;d++) acc += wr[d]*Wv[d*256+t];
  Wg[(size_t)t*1536+col]=__float2half(acc);
}

// ---------------- M2[c][e] = scale * (Wq^T Wk)[e][c]  (fp16) ----------------
__global__ __launch_bounds__(256) void k_M(const float* __restrict__ Wq, const float* __restrict__ Wk,
                                           __half* __restrict__ M2h){
  int c = blockIdx.x, e = threadIdx.x;
  float acc = 0.f;
#pragma unroll 8
  for(int d=0; d<256; d++) acc += Wq[d*256+e]*Wk[d*256+c];
  M2h[c*256+e] = __float2half(acc * 0.0625f);  // 256^-0.5
}

// ---------------- x = LN(inputs) -> fp16 ----------------
__global__ __launch_bounds__(256) void k_ln_x(const float* __restrict__ in, const float* __restrict__ g,
                                              const float* __restrict__ bbv, __half* __restrict__ x){
  int row  = blockIdx.x*4 + (threadIdx.x>>6);
  int lane = threadIdx.x&63;
  const float4 v = ((const float4*)(in + (size_t)row*DD))[lane];
  float s  = v.x+v.y+v.z+v.w;
  float ss = v.x*v.x+v.y*v.y+v.z*v.z+v.w*v.w;
  s = wredsum(s); ss = wredsum(ss);
  float m = s*(1.0f/256.0f);
  float r = rsqrtf(ss*(1.0f/256.0f) - m*m + 1e-5f);
  float4 gv = ((const float4*)g)[lane];
  float4 bv = ((const float4*)bbv)[lane];
  float y0=(v.x-m)*r*gv.x+bv.x, y1=(v.y-m)*r*gv.y+bv.y;
  float y2=(v.z-m)*r*gv.z+bv.z, y3=(v.w-m)*r*gv.w+bv.w;
  __half2 h0=__floats2half2_rn(y0,y1), h1=__floats2half2_rn(y2,y3);
  uint2 u; __builtin_memcpy(&u.x,&h0,4); __builtin_memcpy(&u.y,&h1,4);
  ((uint2*)(x + (size_t)row*DD))[lane] = u;
}

// ---------------- initial qs = LN(slots) @ M (once) ----------------
__global__ __launch_bounds__(256) void k_pre(const float* __restrict__ slots, const float* __restrict__ g,
                                             const float* __restrict__ bbv, const __half* __restrict__ M2h,
                                             float* __restrict__ qs){
  int row = blockIdx.x;      // 0..511
  int t = threadIdx.x;
  __shared__ __align__(16) float sn[256];
  __shared__ float red[8];
  float v = slots[row*256 + t];
  float s = wredsum(v), ss = wredsum(v*v);
  int wid=t>>6, lane=t&63;
  if(lane==0){ red[wid]=s; red[4+wid]=ss; }
  __syncthreads();
  float S  = red[0]+red[1]+red[2]+red[3];
  float SS = red[4]+red[5]+red[6]+red[7];
  float m = S*(1.0f/256.0f);
  float r = rsqrtf(SS*(1.0f/256.0f) - m*m + 1e-5f);
  sn[t] = (v-m)*r*g[t]+bbv[t];
  __syncthreads();
  const uint4* w4 = (const uint4*)(M2h + (size_t)t*256);
  float acc=0.f;
#pragma unroll 4
  for(int kk=0;kk<32;kk++){
    U4 w; w.u=w4[kk];
#pragma unroll
    for(int q=0;q<4;q++){
      float2 f=__half22float2(w.h[q]);
      acc += sn[kk*8+2*q]*f.x + sn[kk*8+2*q+1]*f.y;
    }
  }
  qs[row*256+t]=acc;
}

// ---------------- fused attention pass (unchanged): dots+softmax -> w -> partial agg ----------------
__global__ __launch_bounds__(256) void k_att(const __half* __restrict__ x, const float* __restrict__ qs,
                                             float* __restrict__ pagg){
  int b = blockIdx.x>>4;
  int t = threadIdx.x;
  size_t j = (size_t)blockIdx.x*256 + t;
  __shared__ __align__(16) float qt[256][8];
  __shared__ __align__(16) float wl[256][8];
  __shared__ __align__(16) float aggl[4][2048];
  __shared__ float wsl[4][8];
  const float* qb = qs + b*2048;
  for(int e=t;e<2048;e+=256) qt[e&255][e>>8]=qb[e];
  __syncthreads();
  const uint4* xr = (const uint4*)(x + j*DD);
  float pd[8]={0,0,0,0,0,0,0,0};
#pragma unroll 2
  for(int ch=0; ch<32; ch++){
    uint4 u = xr[ch];
    float2 f0=u2f2(u.x), f1=u2f2(u.y), f2=u2f2(u.z), f3=u2f2(u.w);
    float xv[8]={f0.x,f0.y,f1.x,f1.y,f2.x,f2.y,f3.x,f3.y};
    int c0=ch*8;
#pragma unroll
    for(int cc=0;cc<8;cc++){
      const float4* qp=(const float4*)&qt[c0+cc][0];
      float4 qa=qp[0], qc=qp[1];
      float xvv=xv[cc];
      pd[0]+=qa.x*xvv; pd[1]+=qa.y*xvv; pd[2]+=qa.z*xvv; pd[3]+=qa.w*xvv;
      pd[4]+=qc.x*xvv; pd[5]+=qc.y*xvv; pd[6]+=qc.z*xvv; pd[7]+=qc.w*xvv;
    }
  }
  float mx=pd[0];
#pragma unroll
  for(int i=1;i<8;i++) mx=fmaxf(mx,pd[i]);
  float ev[8]; float ssum=0.f;
#pragma unroll
  for(int i=0;i<8;i++){ ev[i]=__expf(pd[i]-mx); ssum+=ev[i]; }
  float inv=1.0f/ssum;
#pragma unroll
  for(int i=0;i<8;i++) wl[t][i]=ev[i]*inv+1e-5f;
  __syncthreads();
  int wid=t>>6, lane=t&63;
  float acc[8][4];
#pragma unroll
  for(int i=0;i<8;i++){ acc[i][0]=0;acc[i][1]=0;acc[i][2]=0;acc[i][3]=0; }
  float ws[8]={0,0,0,0,0,0,0,0};
  for(int r=0;r<64;r++){
    int jl = wid*64 + r;
    uint2 u = ((const uint2*)(x + ((size_t)blockIdx.x*256 + jl)*DD))[lane];
    float2 f01=u2f2(u.x), f23=u2f2(u.y);
    const float4* wp=(const float4*)&wl[jl][0];
    float4 wa=wp[0], wb_=wp[1];
    float wv[8]={wa.x,wa.y,wa.z,wa.w,wb_.x,wb_.y,wb_.z,wb_.w};
    float xv[4]={f01.x,f01.y,f23.x,f23.y};
#pragma unroll
    for(int i=0;i<8;i++){
      acc[i][0]+=wv[i]*xv[0]; acc[i][1]+=wv[i]*xv[1];
      acc[i][2]+=wv[i]*xv[2]; acc[i][3]+=wv[i]*xv[3];
      ws[i]+=wv[i];
    }
  }
#pragma unroll
  for(int i=0;i<8;i++){
    float4 st={acc[i][0],acc[i][1],acc[i][2],acc[i][3]};
    *((float4*)&aggl[wid][i*256 + lane*4])=st;
  }
  if(lane==0){
#pragma unroll
    for(int i=0;i<8;i++) wsl[wid][i]=ws[i];
  }
  __syncthreads();
  float* pb = pagg + (size_t)blockIdx.x*2064;
  for(int e=t;e<2048;e+=256) pb[e]=aggl[0][e]+aggl[1][e]+aggl[2][e]+aggl[3][e];
  if(t<8) pb[2048+t]=wsl[0][t]+wsl[1][t]+wsl[2][t]+wsl[3][t];
}

// ---------------- t_red: reduce pagg -> aggs fp16 (with fac) ----------------
__global__ __launch_bounds__(256) void t_red(const float* __restrict__ pagg, __half* __restrict__ aggs){
  int row=blockIdx.x; int b=row>>3, i=row&7; int t=threadIdx.x;
  const float* pb = pagg + (size_t)b*16*2064;
  float ws=0.f;
#pragma unroll
  for(int ch=0;ch<16;ch++) ws += pb[ch*2064 + 2048 + i];
  float s=0.f;
#pragma unroll
  for(int ch=0;ch<16;ch++) s += pb[ch*2064 + i*256 + t];
  aggs[(size_t)row*256+t] = __float2half(s * (4096.0f/ws));
}

// ---------------- t_gates: gl[512][1536] = [aggs@WC^T+bih | slotsh@Whh^T+bhh] ----------------
// grid 384 = 16 row-tiles(32) x 24 col-tiles(64), 256 thr, 8 out/thread
__global__ __launch_bounds__(256) void t_gates(const __half* __restrict__ aggs,
    const __half* __restrict__ slotsh, const __half* __restrict__ Wg,
    const float* __restrict__ bih, const float* __restrict__ bhh,
    float* __restrict__ gl){
  int rt=blockIdx.x&15, ct=blockIdx.x>>4;
  int t=threadIdx.x;
  int r0=rt*32, c0=ct*64;
  const __half* A = (ct<12)? aggs : slotsh;
  __shared__ __align__(16) float Af[32][264];
  __shared__ __align__(16) float Wf[64][68];
#pragma unroll
  for(int q=0;q<4;q++){
    int u=q*256+t;                 // 1024 uint4 over [32][32]
    int row=u>>5, kk=u&31;
    st8(&Af[row][kk*8], ((const uint4*)(A + ((size_t)(r0+row))*256))[kk]);
  }
  float acc[2][4]={{0,0,0,0},{0,0,0,0}};
  int tx=t&15, ty=t>>4;
  for(int kc=0;kc<4;kc++){
    __syncthreads();
#pragma unroll
    for(int q=0;q<2;q++){
      int u=q*256+t;               // 512 uint4 over [64][8]
      int kk=u>>3, cb=u&7;
      st8(&Wf[kk][cb*8], ((const uint4*)(Wg + (size_t)(kc*64+kk)*1536 + c0))[cb]);
    }
    __syncthreads();
#pragma unroll
    for(int k4=0;k4<16;k4++){
      float4 a0=*(const float4*)&Af[ty][kc*64+k4*4];
      float4 a1=*(const float4*)&Af[ty+16][kc*64+k4*4];
      float av0[4]={a0.x,a0.y,a0.z,a0.w};
      float av1[4]={a1.x,a1.y,a1.z,a1.w};
#pragma unroll
      for(int jj=0;jj<4;jj++){
        float4 wv=*(const float4*)&Wf[k4*4+jj][tx*4];
        acc[0][0]+=av0[jj]*wv.x; acc[0][1]+=av0[jj]*wv.y; acc[0][2]+=av0[jj]*wv.z; acc[0][3]+=av0[jj]*wv.w;
        acc[1][0]+=av1[jj]*wv.x; acc[1][1]+=av1[jj]*wv.y; acc[1][2]+=av1[jj]*wv.z; acc[1][3]+=av1[jj]*wv.w;
      }
    }
  }
  int col=c0+tx*4;
  const float* bb=(ct<12)? bih : bhh;
  int bcol=(ct<12)? col : col-768;
  float4 bv=*(const float4*)&bb[bcol];
  float4 o0={acc[0][0]+bv.x, acc[0][1]+bv.y, acc[0][2]+bv.z, acc[0][3]+bv.w};
  float4 o1={acc[1][0]+bv.x, acc[1][1]+bv.y, acc[1][2]+bv.z, acc[1][3]+bv.w};
  *(float4*)&gl[(size_t)(r0+ty)*1536+col]=o0;
  *(float4*)&gl[(size_t)(r0+ty+16)*1536+col]=o1;
}

// ---------------- t_gruln: GRU nonlinearity + MLP pre-norm ----------------
__global__ __launch_bounds__(512) void t_gruln(const float* __restrict__ gl, const float* __restrict__ slots,
    const float* __restrict__ lm_g, const float* __restrict__ lm_b,
    float* __restrict__ hb, __half* __restrict__ ysh){
  int t=threadIdx.x;
  int r=t>>8, c=t&255; int row=blockIdx.x*2+r;
  __shared__ float redS[2][4], redQ[2][4];
  const float* gr = gl + (size_t)row*1536;
  float gir=gr[c], giz=gr[256+c], gin=gr[512+c];
  float ghr=gr[768+c], ghz=gr[1024+c], ghn=gr[1280+c];
  float hp = slots[(size_t)row*256+c];
  float rr=sigm(gir+ghr), z=sigm(giz+ghz);
  float n=tanhf(gin+rr*ghn);
  float hv=(1.0f-z)*n+z*hp;
  hb[(size_t)row*256+c]=hv;
  float s=wredsum(hv), ss=wredsum(hv*hv);
  if((t&63)==0){ redS[r][(t>>6)&3]=s; redQ[r][(t>>6)&3]=ss; }
  __syncthreads();
  float S=redS[r][0]+redS[r][1]+redS[r][2]+redS[r][3];
  float SS=redQ[r][0]+redQ[r][1]+redQ[r][2]+redQ[r][3];
  float m=S*(1.0f/256.0f);
  float rs=rsqrtf(SS*(1.0f/256.0f)-m*m+1e-5f);
  ysh[(size_t)row*256+c]=__float2half((hv-m)*rs*lm_g[c]+lm_b[c]);
}

// ---------------- t_mlp1: z1h[512][1024] = lrelu(ysh@W1^T + b1) ----------------
// grid 256 = 16 row-tiles x 16 col-tiles
__global__ __launch_bounds__(256) void t_mlp1(const __half* __restrict__ ysh,
    const __half* __restrict__ W1t, const float* __restrict__ b1,
    __half* __restrict__ z1h){
  int rt=blockIdx.x&15, ct=blockIdx.x>>4;
  int t=threadIdx.x;
  int r0=rt*32, c0=ct*64;
  __shared__ __align__(16) float Af[32][264];
  __shared__ __align__(16) float Wf[64][68];
#pragma unroll
  for(int q=0;q<4;q++){
    int u=q*256+t; int row=u>>5, kk=u&31;
    st8(&Af[row][kk*8], ((const uint4*)(ysh + ((size_t)(r0+row))*256))[kk]);
  }
  float acc[2][4]={{0,0,0,0},{0,0,0,0}};
  int tx=t&15, ty=t>>4;
  for(int kc=0;kc<4;kc++){
    __syncthreads();
#pragma unroll
    for(int q=0;q<2;q++){
      int u=q*256+t; int kk=u>>3, cb=u&7;
      st8(&Wf[kk][cb*8], ((const uint4*)(W1t + (size_t)(kc*64+kk)*1024 + c0))[cb]);
    }
    __syncthreads();
#pragma unroll
    for(int k4=0;k4<16;k4++){
      float4 a0=*(const float4*)&Af[ty][kc*64+k4*4];
      float4 a1=*(const float4*)&Af[ty+16][kc*64+k4*4];
      float av0[4]={a0.x,a0.y,a0.z,a0.w};
      float av1[4]={a1.x,a1.y,a1.z,a1.w};
#pragma unroll
      for(int jj=0;jj<4;jj++){
        float4 wv=*(const float4*)&Wf[k4*4+jj][tx*4];
        acc[0][0]+=av0[jj]*wv.x; acc[0][1]+=av0[jj]*wv.y; acc[0][2]+=av0[jj]*wv.z; acc[0][3]+=av0[jj]*wv.w;
        acc[1][0]+=av1[jj]*wv.x; acc[1][1]+=av1[jj]*wv.y; acc[1][2]+=av1[jj]*wv.z; acc[1][3]+=av1[jj]*wv.w;
      }
    }
  }
  int col=c0+tx*4;
  float4 bv=*(const float4*)&b1[col];
#pragma unroll
  for(int rr2=0;rr2<2;rr2++){
    float v0=acc[rr2][0]+bv.x, v1=acc[rr2][1]+bv.y, v2=acc[rr2][2]+bv.z, v3=acc[rr2][3]+bv.w;
    v0=v0>0.f?v0:0.01f*v0; v1=v1>0.f?v1:0.01f*v1;
    v2=v2>0.f?v2:0.01f*v2; v3=v3>0.f?v3:0.01f*v3;
    __half2 p0=__floats2half2_rn(v0,v1), p1=__floats2half2_rn(v2,v3);
    uint2 u2; __builtin_memcpy(&u2.x,&p0,4); __builtin_memcpy(&u2.y,&p1,4);
    *(uint2*)&z1h[(size_t)(r0+ty+rr2*16)*1024+col]=u2;
  }
}

// ---------------- t_mlp2p: partial z1h@W2^T, K=1024 split 8x128 ----------------
// grid 512 = 16 row-tiles x 4 col-tiles x 8 k-chunks
__global__ __launch_bounds__(256) void t_mlp2p(const __half* __restrict__ z1h,
    const __half* __restrict__ W2t, float* __restrict__ pp){
  int b=blockIdx.x;
  int rt=b&15, ct=(b>>4)&3, kc=b>>6;
  int t=threadIdx.x;
  int r0=rt*32, c0=ct*64;
  __shared__ __align__(16) float Af[32][136];
  __shared__ __align__(16) float Wf[128][68];
#pragma unroll
  for(int q=0;q<2;q++){
    int u=q*256+t;                 // 512 uint4 over [32][16]
    int row=u>>4, seg=u&15;
    st8(&Af[row][seg*8], ((const uint4*)(z1h + (size_t)(r0+row)*1024 + kc*128))[seg]);
  }
#pragma unroll
  for(int q=0;q<4;q++){
    int u=q*256+t;                 // 1024 uint4 over [128][8]
    int kk=u>>3, cb=u&7;
    st8(&Wf[kk][cb*8], ((const uint4*)(W2t + (size_t)(kc*128+kk)*256 + c0))[cb]);
  }
  __syncthreads();
  float acc[2][4]={{0,0,0,0},{0,0,0,0}};
  int tx=t&15, ty=t>>4;
#pragma unroll
  for(int k4=0;k4<32;k4++){
    float4 a0=*(const float4*)&Af[ty][k4*4];
    float4 a1=*(const float4*)&Af[ty+16][k4*4];
    float av0[4]={a0.x,a0.y,a0.z,a0.w};
    float av1[4]={a1.x,a1.y,a1.z,a1.w};
#pragma unroll
    for(int jj=0;jj<4;jj++){
      float4 wv=*(const float4*)&Wf[k4*4+jj][tx*4];
      acc[0][0]+=av0[jj]*wv.x; acc[0][1]+=av0[jj]*wv.y; acc[0][2]+=av0[jj]*wv.z; acc[0][3]+=av0[jj]*wv.w;
      acc[1][0]+=av1[jj]*wv.x; acc[1][1]+=av1[jj]*wv.y; acc[1][2]+=av1[jj]*wv.z; acc[1][3]+=av1[jj]*wv.w;
    }
  }
  int col=c0+tx*4;
  float4 o0={acc[0][0],acc[0][1],acc[0][2],acc[0][3]};
  float4 o1={acc[1][0],acc[1][1],acc[1][2],acc[1][3]};
  *(float4*)&pp[((size_t)kc*512 + r0+ty)*256+col]=o0;
  *(float4*)&pp[((size_t)kc*512 + r0+ty+16)*256+col]=o1;
}

// ---------------- t_fin: reduce partials + residual; slot-LN + qs (non-last) ----------------
__global__ __launch_bounds__(512) void t_fin(const float* __restrict__ hb, const float* __restrict__ pp,
    const float* __restrict__ b2, const float* __restrict__ ls_g, const float* __restrict__ ls_b,
    const __half* __restrict__ M2h, float* __restrict__ dst,
    __half* __restrict__ slotsh, float* __restrict__ qs, int last){
  int t=threadIdx.x;
  int r=t>>8, c=t&255; int row=blockIdx.x*2+r;
  __shared__ float ysl[2][256];
  __shared__ float redS[2][4], redQ[2][4];
  float s = hb[(size_t)row*256+c] + b2[c];
#pragma unroll
  for(int kc=0;kc<8;kc++) s += pp[((size_t)kc*512+row)*256+c];
  dst[(size_t)row*256+c]=s;
  if(last) return;
  slotsh[(size_t)row*256+c]=__float2half(s);
  float su=wredsum(s), sq=wredsum(s*s);
  if((t&63)==0){ redS[r][(t>>6)&3]=su; redQ[r][(t>>6)&3]=sq; }
  __syncthreads();
  float S=redS[r][0]+redS[r][1]+redS[r][2]+redS[r][3];
  float SS=redQ[r][0]+redQ[r][1]+redQ[r][2]+redQ[r][3];
  float m=S*(1.0f/256.0f);
  float rs=rsqrtf(SS*(1.0f/256.0f)-m*m+1e-5f);
  ysl[r][c]=(s-m)*rs*ls_g[c]+ls_b[c];
  __syncthreads();
  const uint4* m4=(const uint4*)(M2h+(size_t)c*256);
  float acc=0.f;
#pragma unroll 4
  for(int kk=0;kk<32;kk++){
    U4 w; w.u=m4[kk];
#pragma unroll
    for(int q=0;q<4;q++){
      float2 f=__half22float2(w.h[q]);
      acc += ysl[r][kk*8+2*q]*f.x + ysl[r][kk*8+2*q+1]*f.y;
    }
  }
  qs[(size_t)row*256+c]=acc;
}

extern "C" void kernel_launch(void* const* d_in, const int* in_sizes, int n_in,
                              void* d_out, int out_size, void* d_ws, size_t ws_size,
                              hipStream_t stream){
  const float* inputs=(const float*)d_in[0];
  const float* sinit =(const float*)d_in[1];
  const float* Wq =(const float*)d_in[2];
  const float* Wk =(const float*)d_in[3];
  const float* Wv =(const float*)d_in[4];
  const float* Wih=(const float*)d_in[5];
  const float* Whh=(const float*)d_in[6];
  const float* bih=(const float*)d_in[7];
  const float* bhh=(const float*)d_in[8];
  const float* lin_g=(const float*)d_in[9];
  const float* lin_b=(const float*)d_in[10];
  const float* ls_g=(const float*)d_in[11];
  const float* ls_b=(const float*)d_in[12];
  const float* lm_g=(const float*)d_in[13];
  const float* lm_b=(const float*)d_in[14];
  const float* W1=(const float*)d_in[15];
  const float* b1=(const float*)d_in[16];
  const float* W2=(const float*)d_in[17];
  const float* b2=(const float*)d_in[18];

  char* w=(char*)d_ws;
  __half* x    =(__half*)w; w += (size_t)BB*NN*DD*2;        // 134.2 MB
  float* qs    =(float*)w;  w += 512*256*4;
  float* slots =(float*)w;  w += 512*256*4;
  __half* slotsh=(__half*)w; w += 512*256*2;
  float* pagg  =(float*)w;  w += (size_t)1024*2064*4;       // 8.45 MB
  __half* M2h  =(__half*)w; w += 256*256*2;
  __half* Wg   =(__half*)w; w += 256*1536*2;
  __half* W1t  =(__half*)w; w += 256*1024*2;
  __half* W2t  =(__half*)w; w += 1024*256*2;
  __half* aggs =(__half*)w; w += 512*256*2;
  float* gl    =(float*)w;  w += (size_t)512*1536*4;        // 3.1 MB
  float* hb    =(float*)w;  w += 512*256*4;
  __half* ysh  =(__half*)w; w += 512*256*2;
  __half* z1h  =(__half*)w; w += (size_t)512*1024*2;
  float* pp    =(float*)w;  w += (size_t)8*512*256*4;       // 4.2 MB

  hipLaunchKernelGGL(k_prep, dim3(1664), dim3(256), 0, stream,
                     Whh, W1, W2, sinit, Wg, W1t, W2t, slots, slotsh);
  hipLaunchKernelGGL(k_WC,   dim3(768),  dim3(256), 0, stream, Wih, Wv, Wg);
  hipLaunchKernelGGL(k_M,    dim3(256),  dim3(256), 0, stream, Wq, Wk, M2h);
  hipLaunchKernelGGL(k_ln_x, dim3(65536),dim3(256), 0, stream, inputs, lin_g, lin_b, x);
  hipLaunchKernelGGL(k_pre,  dim3(512),  dim3(256), 0, stream, slots, ls_g, ls_b, M2h, qs);
  for(int it=0; it<NITER; ++it){
    int last = (it==NITER-1);
    float* dst = last ? (float*)d_out : slots;
    hipLaunchKernelGGL(k_att,   dim3(1024), dim3(256), 0, stream, x, qs, pagg);
    hipLaunchKernelGGL(t_red,   dim3(512),  dim3(256), 0, stream, pagg, aggs);
    hipLaunchKernelGGL(t_gates, dim3(384),  dim3(256), 0, stream, aggs, slotsh, Wg, bih, bhh, gl);
    hipLaunchKernelGGL(t_gruln, dim3(256),  dim3(512), 0, stream, gl, slots, lm_g, lm_b, hb, ysh);
    hipLaunchKernelGGL(t_mlp1,  dim3(256),  dim3(256), 0, stream, ysh, W1t, b1, z1h);
    hipLaunchKernelGGL(t_mlp2p, dim3(512),  dim3(256), 0, stream, z1h, W2t, pp);
    hipLaunchKernelGGL(t_fin,   dim3(256),  dim3(512), 0, stream, hb, pp, b2, ls_g, ls_b, M2h,
                       dst, slotsh, qs, last);
  }
}